// Round 12
// baseline (317.731 us; speedup 1.0000x reference)
//
#include <hip/hip_runtime.h>
#include <math.h>

// Problem constants
#define Bn 2
#define Sn 512
#define Hn 128
#define NHn 4
#define Dn 32
#define BAGn 5
#define NMETAn 16
#define ROWS 1024
#define NBn 2
#define Tt 257

#define NEGF (-4294967295.0f)
#define INV_SQRT_D 0.17677669529663687f
#define SQRT_H 11.313708498984761f
#define EPS_EMB 1e-5f
#define EPSF 1e-8f

// workspace float offsets
#define OFF_QN    0
#define OFF_Q     131072
#define OFF_K     262144
#define OFF_V     393216
#define OFF_O     524288

static __device__ __forceinline__ float red64(float v) {
#pragma unroll
    for (int m = 1; m < 64; m <<= 1) v += __shfl_xor(v, m, 64);
    return v;
}
static __device__ __forceinline__ float red64max(float v) {
#pragma unroll
    for (int m = 1; m < 64; m <<= 1) v = fmaxf(v, __shfl_xor(v, m, 64));
    return v;
}

// LayerNorm over a 128-float smem array; threads t<128 get y, others 0.
// Uses wsum[0..3]; includes its own barriers.
static __device__ __forceinline__ float ln128(
    const float* arr, int t, float eps,
    const float* g, const float* bta, int goff, float* wsum)
{
    float x = (t < 128) ? arr[t] : 0.f;
    float s1 = red64(x);
    if ((t & 63) == 0 && t < 128) wsum[t >> 6] = s1;
    __syncthreads();
    float mean = (wsum[0] + wsum[1]) * (1.f / 128.f);
    float dlt = x - mean;
    float s2 = red64((t < 128) ? dlt * dlt : 0.f);
    if ((t & 63) == 0 && t < 128) wsum[2 + (t >> 6)] = s2;
    __syncthreads();
    float var = (wsum[2] + wsum[3]) * (1.f / 128.f);
    if (t >= 128) return 0.f;
    return dlt * rsqrtf(var + eps) * g[goff + t] + bta[goff + t];
}

// ===========================================================================
// Embed: ONE row per block (1024 blocks, 256 threads, 4 blocks/CU).
// embed -> embLN -> keep -> attnLN(0) -> QKV(0).
// ===========================================================================
__global__ __launch_bounds__(256) void embed_qkv_kernel(
    const int* __restrict__ ids, const float* __restrict__ meta,
    const int* __restrict__ cats,
    const float* __restrict__ item_w, const float* __restrict__ cat_w,
    const float* __restrict__ numW, const float* __restrict__ numb,
    const float* __restrict__ fusW, const float* __restrict__ fusb,
    const float* __restrict__ elng, const float* __restrict__ elnb,
    const float* __restrict__ alng, const float* __restrict__ alnb,
    const float* __restrict__ QW, const float* __restrict__ Qb,
    const float* __restrict__ KW, const float* __restrict__ Kb,
    const float* __restrict__ VW, const float* __restrict__ Vb,
    const float* __restrict__ posK, const float* __restrict__ posV,
    float* __restrict__ Qn, float* __restrict__ Q,
    float* __restrict__ K, float* __restrict__ V)
{
    int r = blockIdx.x, t = threadIdx.x;
    __shared__ float comb[256], xs[128], qs[128], parts[128], pk[128], pv[128];
    __shared__ float wsum[4];
    __shared__ int idv;
    if (t == 0) idv = ids[r];
    __syncthreads();
    int id = idv;
    if (t < 128) {
        comb[t] = item_w[id * Hn + t] * SQRT_H;
    } else if (t < 192) {
        int c = t - 128;
        float acc = numb[c];
#pragma unroll
        for (int m2 = 0; m2 < NMETAn; ++m2)
            acc += meta[r * NMETAn + m2] * numW[c * NMETAn + m2];
        comb[t] = acc;
    } else {
        int c = t - 192;
        float ca = 0.f; int cnt = 0;
#pragma unroll
        for (int k2 = 0; k2 < BAGn; ++k2) {
            int cc2 = cats[r * BAGn + k2];
            if (cc2 != 0) { ca += cat_w[cc2 * 64 + c]; cnt++; }
        }
        comb[t] = ca / (float)(cnt > 0 ? cnt : 1);
    }
    __syncthreads();
    int h = t & 127, kh = t >> 7;
    // fusion GEMM: K=256, split-k 2x128 (float4 weight rows)
    {
        const float4* w4p = (const float4*)(fusW + h * 256 + kh * 128);
        const float* c0 = comb + kh * 128;
        float a0 = 0.f, a1 = 0.f;
#pragma unroll 8
        for (int k4 = 0; k4 < 32; ++k4) {
            float4 w4 = w4p[k4];
            int k = k4 * 4;
            a0 += c0[k] * w4.x + c0[k + 1] * w4.y;
            a1 += c0[k + 2] * w4.z + c0[k + 3] * w4.w;
        }
        float A = a0 + a1;
        if (kh) parts[h] = A;
        __syncthreads();
        if (!kh) xs[h] = A + parts[h] + fusb[h];
    }
    __syncthreads();
    // emb LN + keep
    {
        float y = ln128(xs, t, EPS_EMB, elng, elnb, 0, wsum);
        __syncthreads();
        if (t < 128) xs[t] = (id == 0) ? 0.f : y;
    }
    __syncthreads();
    // attn LN (nb=0)
    {
        float qn = ln128(xs, t, EPSF, alng, alnb, 0, wsum);
        __syncthreads();
        if (t < 128) { qs[t] = qn; Qn[r * 128 + t] = qn; }
    }
    __syncthreads();
    // QKV(0): split-k 2x64
    {
        const float4* qw4 = (const float4*)(QW + h * 128 + kh * 64);
        const float4* kw4 = (const float4*)(KW + h * 128 + kh * 64);
        const float4* vw4 = (const float4*)(VW + h * 128 + kh * 64);
        const float* qp = qs + kh * 64;
        const float* xp = xs + kh * 64;
        float aq = 0.f, ak = 0.f, av = 0.f;
#pragma unroll 4
        for (int k4 = 0; k4 < 16; ++k4) {
            float4 wq = qw4[k4], wk = kw4[k4], wv = vw4[k4];
            int k = k4 * 4;
            aq += qp[k] * wq.x + qp[k + 1] * wq.y + qp[k + 2] * wq.z + qp[k + 3] * wq.w;
            ak += xp[k] * wk.x + xp[k + 1] * wk.y + xp[k + 2] * wk.z + xp[k + 3] * wk.w;
            av += xp[k] * wv.x + xp[k + 1] * wv.y + xp[k + 2] * wv.z + xp[k + 3] * wv.w;
        }
        if (kh) { parts[h] = aq; pk[h] = ak; pv[h] = av; }
        __syncthreads();
        if (!kh) {
            int s = r & (Sn - 1);
            Q[r * 128 + h] = aq + parts[h] + Qb[h];
            K[r * 128 + h] = ak + pk[h] + Kb[h] + posK[s * 128 + h];
            V[r * 128 + h] = av + pv[h] + Vb[h] + posV[s * 128 + h];
        }
    }
}

// ===========================================================================
// Attention (round-11 verified): balanced pairing, fused QT, no PV guard.
// ===========================================================================
static __device__ __forceinline__ void attn_phase(
    int b, int h, int i0, int t,
    const int* __restrict__ ids, const int* __restrict__ tmat,
    const float* __restrict__ Q, const float* __restrict__ K,
    const float* __restrict__ V,
    const float* __restrict__ tKw, const float* __restrict__ tVw,
    float* __restrict__ O,
    float* Kt, float* S, float* QTl, float* ql, float* aparts, float* invl,
    int* tlf)
{
    __syncthreads();
    if (t < 4) tlf[t] = (ids[b * Sn + i0 + t] == 0) ? 1 : 0;
    if (t < 128) {
        int q_ = t >> 5, d = t & 31;
        ql[q_ * 33 + d] = Q[(b * Sn + i0 + q_) * Hn + h * 32 + d];
    }
    __syncthreads();

    for (int tt = t; tt < Tt; tt += 256) {
        const float4* tk4 = (const float4*)(tKw + tt * Hn + h * 32);
        float a0 = 0.f, a1 = 0.f, a2 = 0.f, a3 = 0.f;
#pragma unroll
        for (int dv = 0; dv < 8; ++dv) {
            float4 w4 = tk4[dv];
            int d = dv * 4;
            a0 += ql[d] * w4.x + ql[d + 1] * w4.y + ql[d + 2] * w4.z + ql[d + 3] * w4.w;
            a1 += ql[33 + d] * w4.x + ql[34 + d] * w4.y + ql[35 + d] * w4.z + ql[36 + d] * w4.w;
            a2 += ql[66 + d] * w4.x + ql[67 + d] * w4.y + ql[68 + d] * w4.z + ql[69 + d] * w4.w;
            a3 += ql[99 + d] * w4.x + ql[100 + d] * w4.y + ql[101 + d] * w4.z + ql[102 + d] * w4.w;
        }
        QTl[tt] = a0; QTl[260 + tt] = a1; QTl[520 + tt] = a2; QTl[780 + tt] = a3;
    }

    int tl_any = tlf[0] | tlf[1] | tlf[2] | tlf[3];
    int ntiles = tl_any ? 8 : ((i0 + 3) >> 6) + 1;
    int n = ntiles * 64;

    int iq = t >> 6, jj = t & 63;
    int i_g = i0 + iq;
    int my_tl = tlf[iq];
    const int* trow = tmat + (b * Sn + i_g) * Sn;

    for (int jt = 0; jt < ntiles; ++jt) {
        int j0 = jt * 64;
        __syncthreads();
        for (int f = t; f < 64 * 8; f += 256) {
            int jl = f >> 3, dv = f & 7;
            float4 w4 = *(const float4*)(K + (b * Sn + j0 + jl) * Hn + h * 32 + dv * 4);
            float* kd = &Kt[jl * 33 + dv * 4];
            kd[0] = w4.x; kd[1] = w4.y; kd[2] = w4.z; kd[3] = w4.w;
        }
        __syncthreads();
        int j = j0 + jj;
        float sv = NEGF;
        if (!my_tl && j <= i_g) {
            float acc = 0.f;
#pragma unroll
            for (int d = 0; d < 32; ++d)
                acc += ql[iq * 33 + d] * Kt[jj * 33 + d];
            sv = (acc + QTl[iq * 260 + trow[j]]) * INV_SQRT_D;
        }
        S[iq * 512 + j] = sv;
    }

    float lm = -INFINITY;
    for (int j = jj; j < n; j += 64) lm = fmaxf(lm, S[iq * 512 + j]);
    lm = red64max(lm);
    float ls = 0.f;
    for (int j = jj; j < n; j += 64) {
        float e = expf(S[iq * 512 + j] - lm);
        S[iq * 512 + j] = e;
        ls += e;
    }
    ls = red64(ls);
    if (jj == 0) invl[iq] = 1.f / ls;

    int jq = (t >> 5) & 1, d = t & 31;
    float acc = 0.f;
    for (int jt = 0; jt < ntiles; ++jt) {
        int j0 = jt * 64;
        __syncthreads();
        for (int f = t; f < 64 * 8; f += 256) {
            int jl = f >> 3, dv = f & 7;
            float4 w4 = *(const float4*)(V + (b * Sn + j0 + jl) * Hn + h * 32 + dv * 4);
            float* kd = &Kt[jl * 33 + dv * 4];
            kd[0] = w4.x; kd[1] = w4.y; kd[2] = w4.z; kd[3] = w4.w;
        }
        __syncthreads();
        if (my_tl || j0 <= i_g) {
#pragma unroll 4
            for (int jl = jq * 32; jl < jq * 32 + 32; ++jl) {
                int j = j0 + jl;
                float p = S[iq * 512 + j];
                int tv = trow[j];
                acc += p * (Kt[jl * 33 + d] + tVw[tv * Hn + h * 32 + d]);
            }
        }
    }
    aparts[t] = acc;
    __syncthreads();
    if (t < 128) {
        int iq2 = t >> 5, d2 = t & 31;
        float a = aparts[iq2 * 64 + d2] + aparts[iq2 * 64 + 32 + d2];
        O[(b * Sn + i0 + iq2) * Hn + h * 32 + d2] = a * invl[iq2];
    }
}

__global__ __launch_bounds__(256) void attn_kernel(
    const int* ids, const int* tmat,
    const float* Q, const float* K, const float* V,
    const float* tKw, const float* tVw, float* O)
{
    __shared__ float Kt[64 * 33];
    __shared__ float S[4 * 512];
    __shared__ float QTl[4 * 260];
    __shared__ float ql[4 * 33];
    __shared__ float aparts[256];
    __shared__ float invl[4];
    __shared__ int tlf[4];
    int blk = blockIdx.x, t = threadIdx.x;
    int b8 = blk >> 6, j = blk & 63;
    int b = b8 >> 2, h = b8 & 3;
    attn_phase(b, h, j * 4, t, ids, tmat, Q, K, V, tKw, tVw, O,
               Kt, S, QTl, ql, aparts, invl, tlf);
    attn_phase(b, h, (127 - j) * 4, t, ids, tmat, Q, K, V, tKw, tVw, O,
               Kt, S, QTl, ql, aparts, invl, tlf);
}

// ===========================================================================
// FFN: ONE row per block (1024 blocks). ffn(nb) -> attnLN(nb+1)+QKV or finalLN.
// ===========================================================================
__global__ __launch_bounds__(256) void ffn_qkv_kernel(
    const int* __restrict__ ids, float* __restrict__ Qn,
    const float* __restrict__ O,
    const float* __restrict__ flng, const float* __restrict__ flnb,
    const float* __restrict__ w1W, const float* __restrict__ w1b,
    const float* __restrict__ w2W, const float* __restrict__ w2b,
    const float* __restrict__ alng, const float* __restrict__ alnb,
    const float* __restrict__ QW, const float* __restrict__ Qb,
    const float* __restrict__ KW, const float* __restrict__ Kb,
    const float* __restrict__ VW, const float* __restrict__ Vb,
    const float* __restrict__ posK, const float* __restrict__ posV,
    float* __restrict__ Q, float* __restrict__ K, float* __restrict__ V,
    const float* __restrict__ llng, const float* __restrict__ llnb,
    float* __restrict__ out, int nb, int last)
{
    int r = blockIdx.x, t = threadIdx.x;
    __shared__ float ys[128], h1s[128], qs[128], parts[128], pk[128], pv[128];
    __shared__ float wsum[4];
    if (t < 128) ys[t] = Qn[r * 128 + t] + O[r * 128 + t];
    __syncthreads();
    // fwd LN
    {
        float yv = ln128(ys, t, EPSF, flng, flnb, nb * 128, wsum);
        __syncthreads();
        if (t < 128) ys[t] = yv;
    }
    __syncthreads();
    int h = t & 127, kh = t >> 7;
    // GEMM1 + gelu
    {
        const float4* w4p = (const float4*)(w1W + nb * 16384 + h * 128 + kh * 64);
        const float* yp = ys + kh * 64;
        float a0 = 0.f, a1 = 0.f;
#pragma unroll 4
        for (int k4 = 0; k4 < 16; ++k4) {
            float4 w4 = w4p[k4];
            int k = k4 * 4;
            a0 += yp[k] * w4.x + yp[k + 1] * w4.y;
            a1 += yp[k + 2] * w4.z + yp[k + 3] * w4.w;
        }
        float A = a0 + a1;
        if (kh) parts[h] = A;
        __syncthreads();
        if (!kh) {
            float v0 = A + parts[h] + w1b[nb * 128 + h];
            h1s[h] = 0.5f * v0 * (1.f + erff(v0 * 0.70710678118654752f));
        }
    }
    __syncthreads();
    // GEMM2 + residual + keep
    {
        const float4* w4p = (const float4*)(w2W + nb * 16384 + h * 128 + kh * 64);
        const float* yp = h1s + kh * 64;
        float a0 = 0.f, a1 = 0.f;
#pragma unroll 4
        for (int k4 = 0; k4 < 16; ++k4) {
            float4 w4 = w4p[k4];
            int k = k4 * 4;
            a0 += yp[k] * w4.x + yp[k + 1] * w4.y;
            a1 += yp[k + 2] * w4.z + yp[k + 3] * w4.w;
        }
        float A = a0 + a1;
        __syncthreads();
        if (kh) parts[h] = A;
        __syncthreads();
        if (!kh) {
            float z = A + parts[h] + w2b[nb * 128 + h] + ys[h];
            h1s[h] = (ids[r] == 0) ? 0.f : z;
        }
    }
    __syncthreads();

    if (last) {
        float y = ln128(h1s, t, EPSF, llng, llnb, 0, wsum);
        if (t < 128) out[r * 128 + t] = y;
        return;
    }

    // attn LN(nb+1) + QKV(nb+1)
    int nq = nb + 1;
    {
        float qn = ln128(h1s, t, EPSF, alng, alnb, nq * 128, wsum);
        __syncthreads();
        if (t < 128) { qs[t] = qn; Qn[r * 128 + t] = qn; }
    }
    __syncthreads();
    {
        const float4* qw4 = (const float4*)(QW + nq * 16384 + h * 128 + kh * 64);
        const float4* kw4 = (const float4*)(KW + nq * 16384 + h * 128 + kh * 64);
        const float4* vw4 = (const float4*)(VW + nq * 16384 + h * 128 + kh * 64);
        const float* qp = qs + kh * 64;
        const float* xp = h1s + kh * 64;
        float aq = 0.f, ak = 0.f, av = 0.f;
#pragma unroll 4
        for (int k4 = 0; k4 < 16; ++k4) {
            float4 wq = qw4[k4], wk = kw4[k4], wv = vw4[k4];
            int k = k4 * 4;
            aq += qp[k] * wq.x + qp[k + 1] * wq.y + qp[k + 2] * wq.z + qp[k + 3] * wq.w;
            ak += xp[k] * wk.x + xp[k + 1] * wk.y + xp[k + 2] * wk.z + xp[k + 3] * wk.w;
            av += xp[k] * wv.x + xp[k + 1] * wv.y + xp[k + 2] * wv.z + xp[k + 3] * wv.w;
        }
        if (kh) { parts[h] = aq; pk[h] = ak; pv[h] = av; }
        __syncthreads();
        if (!kh) {
            int s = r & (Sn - 1);
            Q[r * 128 + h] = aq + parts[h] + Qb[nq * 128 + h];
            K[r * 128 + h] = ak + pk[h] + Kb[nq * 128 + h] + posK[s * 128 + h];
            V[r * 128 + h] = av + pv[h] + Vb[nq * 128 + h] + posV[s * 128 + h];
        }
    }
}

// ---------------------------------------------------------------------------
extern "C" void kernel_launch(void* const* d_in, const int* in_sizes, int n_in,
                              void* d_out, int out_size, void* d_ws, size_t ws_size,
                              hipStream_t stream) {
    const int*   ids   = (const int*)  d_in[0];
    const float* meta  = (const float*)d_in[1];
    const int*   cats  = (const int*)  d_in[2];
    const int*   tmat  = (const int*)  d_in[3];
    const float* itemw = (const float*)d_in[4];
    const float* catw  = (const float*)d_in[5];
    const float* numW  = (const float*)d_in[6];
    const float* numb  = (const float*)d_in[7];
    const float* fusW  = (const float*)d_in[8];
    const float* fusb  = (const float*)d_in[9];
    const float* elng  = (const float*)d_in[10];
    const float* elnb  = (const float*)d_in[11];
    const float* posK  = (const float*)d_in[12];
    const float* posV  = (const float*)d_in[13];
    const float* tKw   = (const float*)d_in[14];
    const float* tVw   = (const float*)d_in[15];
    const float* alng  = (const float*)d_in[16];
    const float* alnb  = (const float*)d_in[17];
    const float* QW    = (const float*)d_in[18];
    const float* Qb    = (const float*)d_in[19];
    const float* KW    = (const float*)d_in[20];
    const float* Kb    = (const float*)d_in[21];
    const float* VW    = (const float*)d_in[22];
    const float* Vb    = (const float*)d_in[23];
    const float* flng  = (const float*)d_in[24];
    const float* flnb  = (const float*)d_in[25];
    const float* w1W   = (const float*)d_in[26];
    const float* w1b   = (const float*)d_in[27];
    const float* w2W   = (const float*)d_in[28];
    const float* w2b   = (const float*)d_in[29];
    const float* llng  = (const float*)d_in[30];
    const float* llnb  = (const float*)d_in[31];
    (void)in_sizes; (void)n_in; (void)out_size; (void)ws_size;

    float* ws = (float*)d_ws;
    float* Qn   = ws + OFF_QN;
    float* Q    = ws + OFF_Q;
    float* K    = ws + OFF_K;
    float* V    = ws + OFF_V;
    float* O    = ws + OFF_O;
    float* out  = (float*)d_out;

    embed_qkv_kernel<<<ROWS, 256, 0, stream>>>(
        ids, meta, cats, itemw, catw, numW, numb, fusW, fusb, elng, elnb,
        alng, alnb, QW, Qb, KW, Kb, VW, Vb, posK, posV, Qn, Q, K, V);
    for (int nb = 0; nb < NBn; ++nb) {
        attn_kernel<<<512, 256, 0, stream>>>(ids, tmat, Q, K, V, tKw, tVw, O);
        ffn_qkv_kernel<<<ROWS, 256, 0, stream>>>(
            ids, Qn, O, flng, flnb, w1W, w1b, w2W, w2b,
            alng, alnb, QW, Qb, KW, Kb, VW, Vb, posK, posV,
            Q, K, V, llng, llnb, out, nb, (nb == NBn - 1) ? 1 : 0);
    }
}

// Round 13
// 277.533 us; speedup vs baseline: 1.1448x; 1.1448x over previous
//
#include <hip/hip_runtime.h>
#include <math.h>

// Problem constants
#define Bn 2
#define Sn 512
#define Hn 128
#define NHn 4
#define Dn 32
#define BAGn 5
#define NMETAn 16
#define ROWS 1024
#define NBn 2
#define Tt 257

#define NEGF (-4294967295.0f)
#define INV_SQRT_D 0.17677669529663687f
#define SQRT_H 11.313708498984761f
#define EPS_EMB 1e-5f
#define EPSF 1e-8f

// workspace float offsets
#define OFF_QN    0
#define OFF_Q     131072
#define OFF_K     262144
#define OFF_V     393216
#define OFF_O     524288

static __device__ __forceinline__ float red64(float v) {
#pragma unroll
    for (int m = 1; m < 64; m <<= 1) v += __shfl_xor(v, m, 64);
    return v;
}
static __device__ __forceinline__ float red64max(float v) {
#pragma unroll
    for (int m = 1; m < 64; m <<= 1) v = fmaxf(v, __shfl_xor(v, m, 64));
    return v;
}

// ===========================================================================
// Embed + embLN + keep + attnLN(0) + QKV(0), 2 rows/block (512 blocks).
// ===========================================================================
__global__ __launch_bounds__(256) void embed_qkv_kernel(
    const int* __restrict__ ids, const float* __restrict__ meta,
    const int* __restrict__ cats,
    const float* __restrict__ item_w, const float* __restrict__ cat_w,
    const float* __restrict__ numW, const float* __restrict__ numb,
    const float* __restrict__ fusW, const float* __restrict__ fusb,
    const float* __restrict__ elng, const float* __restrict__ elnb,
    const float* __restrict__ alng, const float* __restrict__ alnb,
    const float* __restrict__ QW, const float* __restrict__ Qb,
    const float* __restrict__ KW, const float* __restrict__ Kb,
    const float* __restrict__ VW, const float* __restrict__ Vb,
    const float* __restrict__ posK, const float* __restrict__ posV,
    float* __restrict__ Qn, float* __restrict__ Q,
    float* __restrict__ K, float* __restrict__ V)
{
    int r0 = blockIdx.x * 2, t = threadIdx.x;
    __shared__ float combs[512], xs[256], qs[256], parts[256], pk[256], pv[256];
    __shared__ float wsum[8];
    __shared__ int idl[2];
    if (t < 2) idl[t] = ids[r0 + t];
    __syncthreads();
    { int r = t >> 7, c = t & 127; combs[r * 256 + c] = item_w[idl[r] * Hn + c] * SQRT_H; }
    if (t < 128) {
        int r = t >> 6, c = t & 63;
        float acc = numb[c];
#pragma unroll
        for (int m2 = 0; m2 < NMETAn; ++m2)
            acc += meta[(r0 + r) * NMETAn + m2] * numW[c * NMETAn + m2];
        combs[r * 256 + 128 + c] = acc;
    } else {
        int u = t - 128, r = u >> 6, c = u & 63;
        float ca = 0.f; int cnt = 0;
#pragma unroll
        for (int k2 = 0; k2 < BAGn; ++k2) {
            int cc2 = cats[(r0 + r) * BAGn + k2];
            if (cc2 != 0) { ca += cat_w[cc2 * 64 + c]; cnt++; }
        }
        combs[r * 256 + 192 + c] = ca / (float)(cnt > 0 ? cnt : 1);
    }
    __syncthreads();
    int h = t & 127, kh = t >> 7;
    // fusion GEMM: K=256 split-k 2x128; deep unroll -> 16 w4 loads in flight
    {
        const float4* w4p = (const float4*)(fusW + h * 256 + kh * 128);
        const float* c0 = combs + kh * 128;
        const float* c1 = combs + 256 + kh * 128;
        float a0 = 0.f, a1 = 0.f, b0 = 0.f, b1 = 0.f;
#pragma unroll 16
        for (int k4 = 0; k4 < 32; ++k4) {
            float4 w4 = w4p[k4];
            int k = k4 * 4;
            a0 += c0[k] * w4.x + c0[k + 1] * w4.y;
            a1 += c0[k + 2] * w4.z + c0[k + 3] * w4.w;
            b0 += c1[k] * w4.x + c1[k + 1] * w4.y;
            b1 += c1[k + 2] * w4.z + c1[k + 3] * w4.w;
        }
        float A0 = a0 + a1, A1 = b0 + b1;
        if (kh) { parts[h] = A0; parts[128 + h] = A1; }
        __syncthreads();
        if (!kh) {
            xs[h] = A0 + parts[h] + fusb[h];
            xs[128 + h] = A1 + parts[128 + h] + fusb[h];
        }
    }
    __syncthreads();
    int w_ = t >> 6, row = w_ >> 1, l = t & 63, ch = ((w_ & 1) << 6) + l;
    float x = xs[row * 128 + ch];
    float s1 = red64(x);
    if (l == 0) wsum[w_] = s1;
    __syncthreads();
    float mean = (wsum[row * 2] + wsum[row * 2 + 1]) * (1.f / 128.f);
    float dlt = x - mean;
    float s2 = red64(dlt * dlt);
    if (l == 0) wsum[4 + w_] = s2;
    __syncthreads();
    float rstd = rsqrtf((wsum[4 + row * 2] + wsum[4 + row * 2 + 1]) * (1.f / 128.f) + EPS_EMB);
    float xv = dlt * rstd * elng[ch] + elnb[ch];
    xv = (idl[row] == 0) ? 0.f : xv;
    __syncthreads();
    xs[row * 128 + ch] = xv;
    __syncthreads();
    s1 = red64(xv);
    if (l == 0) wsum[w_] = s1;
    __syncthreads();
    mean = (wsum[row * 2] + wsum[row * 2 + 1]) * (1.f / 128.f);
    dlt = xv - mean;
    s2 = red64(dlt * dlt);
    if (l == 0) wsum[4 + w_] = s2;
    __syncthreads();
    rstd = rsqrtf((wsum[4 + row * 2] + wsum[4 + row * 2 + 1]) * (1.f / 128.f) + EPSF);
    float qn = dlt * rstd * alng[ch] + alnb[ch];
    qs[row * 128 + ch] = qn;
    Qn[(r0 + row) * 128 + ch] = qn;
    __syncthreads();
    // QKV(0): split-k 2x64; unroll 8 -> 24 w4 loads in flight
    {
        const float4* qw4 = (const float4*)(QW + h * 128 + kh * 64);
        const float4* kw4 = (const float4*)(KW + h * 128 + kh * 64);
        const float4* vw4 = (const float4*)(VW + h * 128 + kh * 64);
        const float* q0p = qs + kh * 64;
        const float* q1p = qs + 128 + kh * 64;
        const float* x0p = xs + kh * 64;
        const float* x1p = xs + 128 + kh * 64;
        float aq0 = 0, aq1 = 0, ak0 = 0, ak1 = 0, av0 = 0, av1 = 0;
#pragma unroll 8
        for (int k4 = 0; k4 < 16; ++k4) {
            float4 wq = qw4[k4], wk = kw4[k4], wv = vw4[k4];
            int k = k4 * 4;
            aq0 += q0p[k] * wq.x + q0p[k + 1] * wq.y + q0p[k + 2] * wq.z + q0p[k + 3] * wq.w;
            aq1 += q1p[k] * wq.x + q1p[k + 1] * wq.y + q1p[k + 2] * wq.z + q1p[k + 3] * wq.w;
            ak0 += x0p[k] * wk.x + x0p[k + 1] * wk.y + x0p[k + 2] * wk.z + x0p[k + 3] * wk.w;
            ak1 += x1p[k] * wk.x + x1p[k + 1] * wk.y + x1p[k + 2] * wk.z + x1p[k + 3] * wk.w;
            av0 += x0p[k] * wv.x + x0p[k + 1] * wv.y + x0p[k + 2] * wv.z + x0p[k + 3] * wv.w;
            av1 += x1p[k] * wv.x + x1p[k + 1] * wv.y + x1p[k + 2] * wv.z + x1p[k + 3] * wv.w;
        }
        if (kh) {
            parts[h] = aq0; parts[128 + h] = aq1;
            pk[h] = ak0; pk[128 + h] = ak1;
            pv[h] = av0; pv[128 + h] = av1;
        }
        __syncthreads();
        if (!kh) {
            int s0 = r0 & (Sn - 1), s1_ = (r0 + 1) & (Sn - 1);
            Q[r0 * 128 + h]       = aq0 + parts[h]       + Qb[h];
            Q[(r0 + 1) * 128 + h] = aq1 + parts[128 + h] + Qb[h];
            K[r0 * 128 + h]       = ak0 + pk[h]          + Kb[h] + posK[s0 * 128 + h];
            K[(r0 + 1) * 128 + h] = ak1 + pk[128 + h]    + Kb[h] + posK[s1_ * 128 + h];
            V[r0 * 128 + h]       = av0 + pv[h]          + Vb[h] + posV[s0 * 128 + h];
            V[(r0 + 1) * 128 + h] = av1 + pv[128 + h]    + Vb[h] + posV[s1_ * 128 + h];
        }
    }
}

// ===========================================================================
// Attention (R11 verified, PV unroll 8): balanced pairing, fused QT.
// ===========================================================================
static __device__ __forceinline__ void attn_phase(
    int b, int h, int i0, int t,
    const int* __restrict__ ids, const int* __restrict__ tmat,
    const float* __restrict__ Q, const float* __restrict__ K,
    const float* __restrict__ V,
    const float* __restrict__ tKw, const float* __restrict__ tVw,
    float* __restrict__ O,
    float* Kt, float* S, float* QTl, float* ql, float* aparts, float* invl,
    int* tlf)
{
    __syncthreads();
    if (t < 4) tlf[t] = (ids[b * Sn + i0 + t] == 0) ? 1 : 0;
    if (t < 128) {
        int q_ = t >> 5, d = t & 31;
        ql[q_ * 33 + d] = Q[(b * Sn + i0 + q_) * Hn + h * 32 + d];
    }
    __syncthreads();

    for (int tt = t; tt < Tt; tt += 256) {
        const float4* tk4 = (const float4*)(tKw + tt * Hn + h * 32);
        float a0 = 0.f, a1 = 0.f, a2 = 0.f, a3 = 0.f;
#pragma unroll
        for (int dv = 0; dv < 8; ++dv) {
            float4 w4 = tk4[dv];
            int d = dv * 4;
            a0 += ql[d] * w4.x + ql[d + 1] * w4.y + ql[d + 2] * w4.z + ql[d + 3] * w4.w;
            a1 += ql[33 + d] * w4.x + ql[34 + d] * w4.y + ql[35 + d] * w4.z + ql[36 + d] * w4.w;
            a2 += ql[66 + d] * w4.x + ql[67 + d] * w4.y + ql[68 + d] * w4.z + ql[69 + d] * w4.w;
            a3 += ql[99 + d] * w4.x + ql[100 + d] * w4.y + ql[101 + d] * w4.z + ql[102 + d] * w4.w;
        }
        QTl[tt] = a0; QTl[260 + tt] = a1; QTl[520 + tt] = a2; QTl[780 + tt] = a3;
    }

    int tl_any = tlf[0] | tlf[1] | tlf[2] | tlf[3];
    int ntiles = tl_any ? 8 : ((i0 + 3) >> 6) + 1;
    int n = ntiles * 64;

    int iq = t >> 6, jj = t & 63;
    int i_g = i0 + iq;
    int my_tl = tlf[iq];
    const int* trow = tmat + (b * Sn + i_g) * Sn;

    for (int jt = 0; jt < ntiles; ++jt) {
        int j0 = jt * 64;
        __syncthreads();
        for (int f = t; f < 64 * 8; f += 256) {
            int jl = f >> 3, dv = f & 7;
            float4 w4 = *(const float4*)(K + (b * Sn + j0 + jl) * Hn + h * 32 + dv * 4);
            float* kd = &Kt[jl * 33 + dv * 4];
            kd[0] = w4.x; kd[1] = w4.y; kd[2] = w4.z; kd[3] = w4.w;
        }
        __syncthreads();
        int j = j0 + jj;
        float sv = NEGF;
        if (!my_tl && j <= i_g) {
            float acc = 0.f;
#pragma unroll
            for (int d = 0; d < 32; ++d)
                acc += ql[iq * 33 + d] * Kt[jj * 33 + d];
            sv = (acc + QTl[iq * 260 + trow[j]]) * INV_SQRT_D;
        }
        S[iq * 512 + j] = sv;
    }

    float lm = -INFINITY;
    for (int j = jj; j < n; j += 64) lm = fmaxf(lm, S[iq * 512 + j]);
    lm = red64max(lm);
    float ls = 0.f;
    for (int j = jj; j < n; j += 64) {
        float e = expf(S[iq * 512 + j] - lm);
        S[iq * 512 + j] = e;
        ls += e;
    }
    ls = red64(ls);
    if (jj == 0) invl[iq] = 1.f / ls;

    int jq = (t >> 5) & 1, d = t & 31;
    float acc = 0.f;
    for (int jt = 0; jt < ntiles; ++jt) {
        int j0 = jt * 64;
        __syncthreads();
        for (int f = t; f < 64 * 8; f += 256) {
            int jl = f >> 3, dv = f & 7;
            float4 w4 = *(const float4*)(V + (b * Sn + j0 + jl) * Hn + h * 32 + dv * 4);
            float* kd = &Kt[jl * 33 + dv * 4];
            kd[0] = w4.x; kd[1] = w4.y; kd[2] = w4.z; kd[3] = w4.w;
        }
        __syncthreads();
        if (my_tl || j0 <= i_g) {
#pragma unroll 8
            for (int jl = jq * 32; jl < jq * 32 + 32; ++jl) {
                int j = j0 + jl;
                float p = S[iq * 512 + j];
                int tv = trow[j];
                acc += p * (Kt[jl * 33 + d] + tVw[tv * Hn + h * 32 + d]);
            }
        }
    }
    aparts[t] = acc;
    __syncthreads();
    if (t < 128) {
        int iq2 = t >> 5, d2 = t & 31;
        float a = aparts[iq2 * 64 + d2] + aparts[iq2 * 64 + 32 + d2];
        O[(b * Sn + i0 + iq2) * Hn + h * 32 + d2] = a * invl[iq2];
    }
}

__global__ __launch_bounds__(256) void attn_kernel(
    const int* ids, const int* tmat,
    const float* Q, const float* K, const float* V,
    const float* tKw, const float* tVw, float* O)
{
    __shared__ float Kt[64 * 33];
    __shared__ float S[4 * 512];
    __shared__ float QTl[4 * 260];
    __shared__ float ql[4 * 33];
    __shared__ float aparts[256];
    __shared__ float invl[4];
    __shared__ int tlf[4];
    int blk = blockIdx.x, t = threadIdx.x;
    int b8 = blk >> 6, j = blk & 63;
    int b = b8 >> 2, h = b8 & 3;
    attn_phase(b, h, j * 4, t, ids, tmat, Q, K, V, tKw, tVw, O,
               Kt, S, QTl, ql, aparts, invl, tlf);
    attn_phase(b, h, (127 - j) * 4, t, ids, tmat, Q, K, V, tKw, tVw, O,
               Kt, S, QTl, ql, aparts, invl, tlf);
}

// ===========================================================================
// FFN(nb) -> [attnLN(nb+1)+QKV(nb+1)] or [final LN -> out]. 2 rows/block.
// ===========================================================================
__global__ __launch_bounds__(256) void ffn_qkv_kernel(
    const int* __restrict__ ids, float* __restrict__ Qn,
    const float* __restrict__ O,
    const float* __restrict__ flng, const float* __restrict__ flnb,
    const float* __restrict__ w1W, const float* __restrict__ w1b,
    const float* __restrict__ w2W, const float* __restrict__ w2b,
    const float* __restrict__ alng, const float* __restrict__ alnb,
    const float* __restrict__ QW, const float* __restrict__ Qb,
    const float* __restrict__ KW, const float* __restrict__ Kb,
    const float* __restrict__ VW, const float* __restrict__ Vb,
    const float* __restrict__ posK, const float* __restrict__ posV,
    float* __restrict__ Q, float* __restrict__ K, float* __restrict__ V,
    const float* __restrict__ llng, const float* __restrict__ llnb,
    float* __restrict__ out, int nb, int last)
{
    int r0 = blockIdx.x * 2, t = threadIdx.x;
    __shared__ float ys[256], h1s[256], parts[256], pk[256], pv[256];
    __shared__ float wsum[8];
    ys[t] = Qn[r0 * 128 + t] + O[r0 * 128 + t];
    __syncthreads();
    int w_ = t >> 6, row = w_ >> 1, l = t & 63, ch = ((w_ & 1) << 6) + l;
    float x = ys[row * 128 + ch];
    float s1 = red64(x);
    if (l == 0) wsum[w_] = s1;
    __syncthreads();
    float mean = (wsum[row * 2] + wsum[row * 2 + 1]) * (1.f / 128.f);
    float dlt = x - mean;
    float s2 = red64(dlt * dlt);
    if (l == 0) wsum[4 + w_] = s2;
    __syncthreads();
    float rstd = rsqrtf((wsum[4 + row * 2] + wsum[4 + row * 2 + 1]) * (1.f / 128.f) + EPSF);
    float yv = dlt * rstd * flng[nb * 128 + ch] + flnb[nb * 128 + ch];
    __syncthreads();
    ys[row * 128 + ch] = yv;
    __syncthreads();

    int h = t & 127, kh = t >> 7;
    // GEMM1: full unroll -> 16 w4 loads in flight
    {
        const float4* w4p = (const float4*)(w1W + nb * 16384 + h * 128 + kh * 64);
        const float* y0 = ys + kh * 64;
        const float* y1 = ys + 128 + kh * 64;
        float a0 = 0.f, a1 = 0.f, b0 = 0.f, b1 = 0.f;
#pragma unroll 16
        for (int k4 = 0; k4 < 16; ++k4) {
            float4 w4 = w4p[k4];
            int k = k4 * 4;
            a0 += y0[k] * w4.x + y0[k + 1] * w4.y;
            a1 += y0[k + 2] * w4.z + y0[k + 3] * w4.w;
            b0 += y1[k] * w4.x + y1[k + 1] * w4.y;
            b1 += y1[k + 2] * w4.z + y1[k + 3] * w4.w;
        }
        float A0 = a0 + a1, A1 = b0 + b1;
        if (kh) { parts[h] = A0; parts[128 + h] = A1; }
        __syncthreads();
        if (!kh) {
            float v0 = A0 + parts[h] + w1b[nb * 128 + h];
            float v1 = A1 + parts[128 + h] + w1b[nb * 128 + h];
            h1s[h] = 0.5f * v0 * (1.f + erff(v0 * 0.70710678118654752f));
            h1s[128 + h] = 0.5f * v1 * (1.f + erff(v1 * 0.70710678118654752f));
        }
    }
    __syncthreads();
    // GEMM2: full unroll
    {
        const float4* w4p = (const float4*)(w2W + nb * 16384 + h * 128 + kh * 64);
        const float* y0 = h1s + kh * 64;
        const float* y1 = h1s + 128 + kh * 64;
        float a0 = 0.f, a1 = 0.f, b0 = 0.f, b1 = 0.f;
#pragma unroll 16
        for (int k4 = 0; k4 < 16; ++k4) {
            float4 w4 = w4p[k4];
            int k = k4 * 4;
            a0 += y0[k] * w4.x + y0[k + 1] * w4.y;
            a1 += y0[k + 2] * w4.z + y0[k + 3] * w4.w;
            b0 += y1[k] * w4.x + y1[k + 1] * w4.y;
            b1 += y1[k + 2] * w4.z + y1[k + 3] * w4.w;
        }
        float A0 = a0 + a1, A1 = b0 + b1;
        __syncthreads();
        if (kh) { parts[h] = A0; parts[128 + h] = A1; }
        __syncthreads();
        if (!kh) {
            float z0 = A0 + parts[h] + w2b[nb * 128 + h] + ys[h];
            float z1 = A1 + parts[128 + h] + w2b[nb * 128 + h] + ys[128 + h];
            z0 = (ids[r0] == 0) ? 0.f : z0;
            z1 = (ids[r0 + 1] == 0) ? 0.f : z1;
            h1s[h] = z0; h1s[128 + h] = z1;
        }
    }
    __syncthreads();

    if (last) {
        x = h1s[row * 128 + ch];
        s1 = red64(x);
        if (l == 0) wsum[w_] = s1;
        __syncthreads();
        mean = (wsum[row * 2] + wsum[row * 2 + 1]) * (1.f / 128.f);
        dlt = x - mean;
        s2 = red64(dlt * dlt);
        if (l == 0) wsum[4 + w_] = s2;
        __syncthreads();
        rstd = rsqrtf((wsum[4 + row * 2] + wsum[4 + row * 2 + 1]) * (1.f / 128.f) + EPSF);
        out[(r0 + row) * 128 + ch] = dlt * rstd * llng[ch] + llnb[ch];
        return;
    }

    int nq = nb + 1;
    x = h1s[row * 128 + ch];
    s1 = red64(x);
    if (l == 0) wsum[w_] = s1;
    __syncthreads();
    mean = (wsum[row * 2] + wsum[row * 2 + 1]) * (1.f / 128.f);
    dlt = x - mean;
    s2 = red64(dlt * dlt);
    if (l == 0) wsum[4 + w_] = s2;
    __syncthreads();
    rstd = rsqrtf((wsum[4 + row * 2] + wsum[4 + row * 2 + 1]) * (1.f / 128.f) + EPSF);
    float qn = dlt * rstd * alng[nq * 128 + ch] + alnb[nq * 128 + ch];
    __syncthreads();
    ys[row * 128 + ch] = qn;
    Qn[(r0 + row) * 128 + ch] = qn;
    __syncthreads();

    {
        const float4* qw4 = (const float4*)(QW + nq * 16384 + h * 128 + kh * 64);
        const float4* kw4 = (const float4*)(KW + nq * 16384 + h * 128 + kh * 64);
        const float4* vw4 = (const float4*)(VW + nq * 16384 + h * 128 + kh * 64);
        const float* q0p = ys + kh * 64;
        const float* q1p = ys + 128 + kh * 64;
        const float* x0p = h1s + kh * 64;
        const float* x1p = h1s + 128 + kh * 64;
        float aq0 = 0, aq1 = 0, ak0 = 0, ak1 = 0, av0 = 0, av1 = 0;
#pragma unroll 8
        for (int k4 = 0; k4 < 16; ++k4) {
            float4 wq = qw4[k4], wk = kw4[k4], wv = vw4[k4];
            int k = k4 * 4;
            aq0 += q0p[k] * wq.x + q0p[k + 1] * wq.y + q0p[k + 2] * wq.z + q0p[k + 3] * wq.w;
            aq1 += q1p[k] * wq.x + q1p[k + 1] * wq.y + q1p[k + 2] * wq.z + q1p[k + 3] * wq.w;
            ak0 += x0p[k] * wk.x + x0p[k + 1] * wk.y + x0p[k + 2] * wk.z + x0p[k + 3] * wk.w;
            ak1 += x1p[k] * wk.x + x1p[k + 1] * wk.y + x1p[k + 2] * wk.z + x1p[k + 3] * wk.w;
            av0 += x0p[k] * wv.x + x0p[k + 1] * wv.y + x0p[k + 2] * wv.z + x0p[k + 3] * wv.w;
            av1 += x1p[k] * wv.x + x1p[k + 1] * wv.y + x1p[k + 2] * wv.z + x1p[k + 3] * wv.w;
        }
        if (kh) {
            parts[h] = aq0; parts[128 + h] = aq1;
            pk[h] = ak0; pk[128 + h] = ak1;
            pv[h] = av0; pv[128 + h] = av1;
        }
        __syncthreads();
        if (!kh) {
            int s0 = r0 & (Sn - 1), s1_ = (r0 + 1) & (Sn - 1);
            Q[r0 * 128 + h]       = aq0 + parts[h]       + Qb[nq * 128 + h];
            Q[(r0 + 1) * 128 + h] = aq1 + parts[128 + h] + Qb[nq * 128 + h];
            K[r0 * 128 + h]       = ak0 + pk[h]          + Kb[nq * 128 + h] + posK[s0 * 128 + h];
            K[(r0 + 1) * 128 + h] = ak1 + pk[128 + h]    + Kb[nq * 128 + h] + posK[s1_ * 128 + h];
            V[r0 * 128 + h]       = av0 + pv[h]          + Vb[nq * 128 + h] + posV[s0 * 128 + h];
            V[(r0 + 1) * 128 + h] = av1 + pv[128 + h]    + Vb[nq * 128 + h] + posV[s1_ * 128 + h];
        }
    }
}

// ---------------------------------------------------------------------------
extern "C" void kernel_launch(void* const* d_in, const int* in_sizes, int n_in,
                              void* d_out, int out_size, void* d_ws, size_t ws_size,
                              hipStream_t stream) {
    const int*   ids   = (const int*)  d_in[0];
    const float* meta  = (const float*)d_in[1];
    const int*   cats  = (const int*)  d_in[2];
    const int*   tmat  = (const int*)  d_in[3];
    const float* itemw = (const float*)d_in[4];
    const float* catw  = (const float*)d_in[5];
    const float* numW  = (const float*)d_in[6];
    const float* numb  = (const float*)d_in[7];
    const float* fusW  = (const float*)d_in[8];
    const float* fusb  = (const float*)d_in[9];
    const float* elng  = (const float*)d_in[10];
    const float* elnb  = (const float*)d_in[11];
    const float* posK  = (const float*)d_in[12];
    const float* posV  = (const float*)d_in[13];
    const float* tKw   = (const float*)d_in[14];
    const float* tVw   = (const float*)d_in[15];
    const float* alng  = (const float*)d_in[16];
    const float* alnb  = (const float*)d_in[17];
    const float* QW    = (const float*)d_in[18];
    const float* Qb    = (const float*)d_in[19];
    const float* KW    = (const float*)d_in[20];
    const float* Kb    = (const float*)d_in[21];
    const float* VW    = (const float*)d_in[22];
    const float* Vb    = (const float*)d_in[23];
    const float* flng  = (const float*)d_in[24];
    const float* flnb  = (const float*)d_in[25];
    const float* w1W   = (const float*)d_in[26];
    const float* w1b   = (const float*)d_in[27];
    const float* w2W   = (const float*)d_in[28];
    const float* w2b   = (const float*)d_in[29];
    const float* llng  = (const float*)d_in[30];
    const float* llnb  = (const float*)d_in[31];
    (void)in_sizes; (void)n_in; (void)out_size; (void)ws_size;

    float* ws = (float*)d_ws;
    float* Qn   = ws + OFF_QN;
    float* Q    = ws + OFF_Q;
    float* K    = ws + OFF_K;
    float* V    = ws + OFF_V;
    float* O    = ws + OFF_O;
    float* out  = (float*)d_out;

    embed_qkv_kernel<<<ROWS / 2, 256, 0, stream>>>(
        ids, meta, cats, itemw, catw, numW, numb, fusW, fusb, elng, elnb,
        alng, alnb, QW, Qb, KW, Kb, VW, Vb, posK, posV, Qn, Q, K, V);
    for (int nb = 0; nb < NBn; ++nb) {
        attn_kernel<<<512, 256, 0, stream>>>(ids, tmat, Q, K, V, tKw, tVw, O);
        ffn_qkv_kernel<<<ROWS / 2, 256, 0, stream>>>(
            ids, Qn, O, flng, flnb, w1W, w1b, w2W, w2b,
            alng, alnb, QW, Qb, KW, Kb, VW, Vb, posK, posV,
            Q, K, V, llng, llnb, out, nb, (nb == NBn - 1) ? 1 : 0);
    }
}